// Round 8
// baseline (2968.994 us; speedup 1.0000x reference)
//
#include <hip/hip_runtime.h>

#define NN   4096
#define TT   17
#define PP   16
#define NTOT (NN*TT)          // 69632
#define NIT  47               // reference CG_ITERS (fixed)
#define KSL  512              // k-slice per block (8 k-blocks)
#define NKB  8
#define NGB  2048             // gemm grid = 256 row-blocks x 8 k-blocks

// ws float offsets (ws is 256 MiB; we use ~4 MB)
#define O_PART 0                    // [2048][64]: del at +0..16, gam at +32..48
#define O_SC   (NGB*64)             // scale[0..16], rhs[32..48]
#define O_ALBE (O_SC + 64)          // alpha[0..16], beta[32..48]
#define O_APGP (O_ALBE + 64)        // aprev[0..16], gprev[32..48]
#define O_R    (O_APGP + 64)
#define O_P    (O_R + NTOT)
#define O_S    (O_P + NTOT)
#define O_X    (O_S + NTOT)
#define O_W0   (O_X + NTOT)         // 8 k-split partials of K@r, each NTOT

// ---- setup: per-column sum of squares of [y | Z] ----
__global__ void k_ssq(const float* __restrict__ y, const float* __restrict__ Z,
                      float* __restrict__ ws) {
    __shared__ float red[TT];
    int t = threadIdx.x;
    if (t < TT) red[t] = 0.f;
    __syncthreads();
    int n = blockIdx.x*256 + t;
    atomicAdd(&red[0], y[n]*y[n]);
    #pragma unroll
    for (int j = 0; j < PP; ++j) { float v = Z[n*PP + j]; atomicAdd(&red[j+1], v*v); }
    __syncthreads();
    if (t < TT) ws[O_PART + blockIdx.x*64 + t] = red[t];
}

// ---- setup: scale / rhs-norm per column ----
__global__ void k_scale(float* __restrict__ ws) {
    int t = threadIdx.x;
    if (t < TT) {
        float s = 0.f;
        #pragma unroll
        for (int i = 0; i < 16; ++i) s += ws[O_PART + i*64 + t];
        float scale, rh;
        if (t == 0) {
            rh = sqrtf(s); if (rh < 1e-10f) rh = 1.f;
            scale = 1.f/rh;
        } else {
            float zn = sqrtf(s);
            float bn = zn/(zn + 1e-10f);
            rh = (bn < 1e-10f) ? 1.f : bn;
            scale = 1.f/((zn + 1e-10f)*rh);
        }
        ws[O_SC + t] = scale; ws[O_SC + 32 + t] = rh;
    }
}

// ---- setup: r0 = b_norm ([c][n] layout), zero p,s,x ----
__global__ void k_init(const float* __restrict__ y, const float* __restrict__ Z,
                       float* __restrict__ ws) {
    int e = blockIdx.x*256 + threadIdx.x;     // 272*256 == NTOT exactly
    int c = e >> 12, n = e & (NN-1);
    float raw = (c == 0) ? y[n] : Z[n*PP + (c-1)];
    ws[O_R + e] = raw * ws[O_SC + c];
    ws[O_P + e] = 0.f; ws[O_S + e] = 0.f; ws[O_X + e] = 0.f;
}

// ---- per-iter GEMM: async global_load_lds staging of full K/r tiles,
//      66 KB LDS -> 2 blocks/CU, barrier-free inner compute ----
__global__ __launch_bounds__(256, 2)
void k_gemm(const float* __restrict__ Km, float* __restrict__ ws) {
    const int t    = threadIdx.x, b = blockIdx.x;
    const int lane = t & 63, w = t >> 6;      // 4 waves
    const int rb   = b >> 3, kb = b & 7;      // 256 row-blocks x 8 k-blocks
    const int row0 = rb*16 + w*4;             // 4 rows per wave

    const float* r_ = ws + O_R;
    float* wp = ws + O_W0 + kb*NTOT;

    __shared__ float Kl[16*KSL];              // 32 KB: [local_row][k]
    __shared__ float rl[TT*KSL];              // 34 KB: [c][k]; reused for reduce
    __shared__ float redd[TT], redg[TT];

    if (t < TT) { redd[t] = 0.f; redg[t] = 0.f; }

    // ---- async stage: each instr = 64 lanes x 16 B = 1 KB into LDS ----
    #pragma unroll
    for (int rr = 0; rr < 4; ++rr) {
        const float* g = Km + (size_t)(row0 + rr)*NN + kb*KSL + 4*lane;
        __builtin_amdgcn_global_load_lds(g,       &Kl[(w*4+rr)*KSL],       16, 0, 0);
        __builtin_amdgcn_global_load_lds(g + 256, &Kl[(w*4+rr)*KSL + 256], 16, 0, 0);
    }
    for (int c = w; c < TT; c += 4) {
        const float* g = r_ + c*NN + kb*KSL + 4*lane;
        __builtin_amdgcn_global_load_lds(g,       &rl[c*KSL],       16, 0, 0);
        __builtin_amdgcn_global_load_lds(g + 256, &rl[c*KSL + 256], 16, 0, 0);
    }
    __syncthreads();      // vmcnt drain + barrier: whole tile resident

    float acc[4][TT];
    #pragma unroll
    for (int rr = 0; rr < 4; ++rr)
        #pragma unroll
        for (int c = 0; c < TT; ++c) acc[rr][c] = 0.f;

    #pragma unroll
    for (int ch = 0; ch < 2; ++ch) {          // 2 chunks x 256 k
        float4 kf[4];
        #pragma unroll
        for (int rr = 0; rr < 4; ++rr)
            kf[rr] = *(const float4*)(Kl + (w*4+rr)*KSL + ch*256 + 4*lane);
        #pragma unroll
        for (int c = 0; c < TT; ++c) {
            float4 rv = *(const float4*)(rl + c*KSL + ch*256 + 4*lane);
            #pragma unroll
            for (int rr = 0; rr < 4; ++rr)
                acc[rr][c] += kf[rr].x*rv.x + kf[rr].y*rv.y + kf[rr].z*rv.z + kf[rr].w*rv.w;
        }
    }

    // partial butterfly: 64 -> 16 lane-classes
    #pragma unroll
    for (int rr = 0; rr < 4; ++rr)
        #pragma unroll
        for (int c = 0; c < TT; ++c) {
            float v = acc[rr][c];
            v += __shfl_xor(v, 32, 64);
            v += __shfl_xor(v, 16, 64);
            acc[rr][c] = v;
        }

    __syncthreads();                          // all waves done reading rl
    float4* part2 = (float4*)rl;              // reuse: [w][c][16] float4(rr)
    if (lane < 16) {
        #pragma unroll
        for (int c = 0; c < TT; ++c)
            part2[(w*TT + c)*16 + lane] =
                make_float4(acc[0][c], acc[1][c], acc[2][c], acc[3][c]);
    }
    __syncthreads();

    if (t < 4*TT) {                           // 68 finish threads
        int w2 = t / TT, c2 = t % TT;
        float4 s = make_float4(0.f, 0.f, 0.f, 0.f);
        #pragma unroll
        for (int i = 0; i < 16; ++i) {
            float4 u = part2[(w2*TT + c2)*16 + i];
            s.x += u.x; s.y += u.y; s.z += u.z; s.w += u.w;
        }
        int row = rb*16 + w2*4;
        *(float4*)(wp + c2*NN + row) = s;     // dwordx4 partial write
        float4 rv = *(const float4*)(r_ + c2*NN + row);
        float dp = rv.x*s.x + rv.y*s.y + rv.z*s.z + rv.w*s.w;
        float gp = rv.x*rv.x + rv.y*rv.y + rv.z*rv.z + rv.w*rv.w;
        atomicAdd(&redd[c2], dp);
        if (kb == 0) atomicAdd(&redg[c2], gp);
    }
    __syncthreads();
    if (t < TT) {
        ws[O_PART + b*64 + t]      = redd[t];
        ws[O_PART + b*64 + 32 + t] = (kb == 0) ? redg[t] : 0.f;
    }
}

// ---- per-iter: reduce 2048 partial slots, compute alpha/beta (pipelined CG) ----
__global__ void k_red(const float* __restrict__ noise, float* __restrict__ ws, int it) {
    __shared__ float sm[8][64];
    int t = threadIdx.x, seg = t >> 6, j = t & 63;   // 512 threads, 8 segments
    float s = 0.f;
    if (j < TT || (j >= 32 && j < 32 + TT)) {
        for (int i = 0; i < NGB/8; ++i)
            s += ws[O_PART + (seg*(NGB/8) + i)*64 + j];
    }
    sm[seg][j] = s;
    __syncthreads();
    if (t < TT) {
        float del = 0.f, gam = 0.f;
        #pragma unroll
        for (int g = 0; g < 8; ++g) { del += sm[g][t]; gam += sm[g][32 + t]; }
        float s2 = noise[0]*noise[0];
        float delta = del + s2*gam;               // r^T (K + s2 I) r
        float beta = 0.f, D = delta;
        if (it > 0) {
            float gp = ws[O_APGP + 32 + t];
            beta = (fabsf(gp) < 1e-30f) ? 0.f : gam/gp;
            float ap = ws[O_APGP + t];
            D = delta - ((fabsf(ap) < 1e-30f) ? 0.f : beta*gam/ap);
        }
        float alpha = (fabsf(D) < 1e-30f) ? 0.f : gam/D;
        ws[O_ALBE + t] = alpha; ws[O_ALBE + 32 + t] = beta;
        ws[O_APGP + t] = alpha; ws[O_APGP + 32 + t] = gam;
    }
}

// ---- per-iter: element-wise p,s,x,r updates (fully coalesced, [c][n] linear) ----
__global__ void k_upd(const float* __restrict__ noise, float* __restrict__ ws,
                      float* __restrict__ out, int last) {
    int e = blockIdx.x*256 + threadIdx.x;     // 272*256 == NTOT
    int c = e >> 12, n = e & (NN-1);
    float s2 = noise[0]*noise[0];
    float al = ws[O_ALBE + c], be = ws[O_ALBE + 32 + c];
    float rv = ws[O_R + e];
    float wv = s2*rv;
    #pragma unroll
    for (int j = 0; j < NKB; ++j) wv += ws[O_W0 + j*NTOT + e];
    float pn = rv + be*ws[O_P + e];
    float sn = wv + be*ws[O_S + e];
    float xn = ws[O_X + e] + al*pn;
    float rn = rv - al*sn;
    ws[O_P + e] = pn; ws[O_S + e] = sn; ws[O_X + e] = xn; ws[O_R + e] = rn;
    if (last) out[n*TT + c] = xn * ws[O_SC + 32 + c];
}

extern "C" void kernel_launch(void* const* d_in, const int* in_sizes, int n_in,
                              void* d_out, int out_size, void* d_ws, size_t ws_size,
                              hipStream_t stream) {
    const float* Km    = (const float*)d_in[0];
    const float* yv    = (const float*)d_in[1];
    const float* Zm    = (const float*)d_in[2];
    const float* noise = (const float*)d_in[3];
    float* out = (float*)d_out;
    float* ws  = (float*)d_ws;

    k_ssq  <<<16, 256, 0, stream>>>(yv, Zm, ws);
    k_scale<<<1,   64, 0, stream>>>(ws);
    k_init <<<272, 256, 0, stream>>>(yv, Zm, ws);
    for (int it = 0; it < NIT; ++it) {
        k_gemm<<<NGB, 256, 0, stream>>>(Km, ws);
        k_red <<<1,   512, 0, stream>>>(noise, ws, it);
        k_upd <<<272, 256, 0, stream>>>(noise, ws, out, it == NIT-1);
    }
}

// Round 9
// 1930.987 us; speedup vs baseline: 1.5376x; 1.5376x over previous
//
#include <hip/hip_runtime.h>

#define NN   4096
#define TT   17
#define PP   16
#define NTOT (NN*TT)          // 69632
#define NIT  47               // reference CG_ITERS (fixed)
#define KSL  1024             // k-slice per block (4 k-blocks)

// ws float offsets
#define O_PART 0               // [512][64]: del at +0..16, gam at +32..48
#define O_SC   (1024*64)       // scale[0..16], rhs[32..48]
#define O_ALBE (O_SC + 64)     // alpha[0..16], beta[32..48]
#define O_APGP (O_ALBE + 64)   // aprev[0..16], gprev[32..48]
#define O_R    (O_APGP + 64)
#define O_P    (O_R + NTOT)
#define O_S    (O_P + NTOT)
#define O_X    (O_S + NTOT)
#define O_W0   (O_X + NTOT)    // 4 k-split partials of K@r, each NTOT

// ---- setup: per-column sum of squares of [y | Z] ----
__global__ void k_ssq(const float* __restrict__ y, const float* __restrict__ Z,
                      float* __restrict__ ws) {
    __shared__ float red[TT];
    int t = threadIdx.x;
    if (t < TT) red[t] = 0.f;
    __syncthreads();
    int n = blockIdx.x*256 + t;
    atomicAdd(&red[0], y[n]*y[n]);
    #pragma unroll
    for (int j = 0; j < PP; ++j) { float v = Z[n*PP + j]; atomicAdd(&red[j+1], v*v); }
    __syncthreads();
    if (t < TT) ws[O_PART + blockIdx.x*64 + t] = red[t];
}

// ---- setup: scale / rhs-norm per column ----
__global__ void k_scale(float* __restrict__ ws) {
    int t = threadIdx.x;
    if (t < TT) {
        float s = 0.f;
        #pragma unroll
        for (int i = 0; i < 16; ++i) s += ws[O_PART + i*64 + t];
        float scale, rh;
        if (t == 0) {
            rh = sqrtf(s); if (rh < 1e-10f) rh = 1.f;
            scale = 1.f/rh;
        } else {
            float zn = sqrtf(s);
            float bn = zn/(zn + 1e-10f);
            rh = (bn < 1e-10f) ? 1.f : bn;
            scale = 1.f/((zn + 1e-10f)*rh);
        }
        ws[O_SC + t] = scale; ws[O_SC + 32 + t] = rh;
    }
}

// ---- setup: r0 = b_norm ([c][n] layout), zero p,s,x ----
__global__ void k_init(const float* __restrict__ y, const float* __restrict__ Z,
                       float* __restrict__ ws) {
    int e = blockIdx.x*256 + threadIdx.x;     // 272*256 == NTOT exactly
    int c = e >> 12, n = e & (NN-1);
    float raw = (c == 0) ? y[n] : Z[n*PP + (c-1)];
    ws[O_R + e] = raw * ws[O_SC + c];
    ws[O_P + e] = 0.f; ws[O_S + e] = 0.f; ws[O_X + e] = 0.f;
}

// ---- per-iter GEMM: 512 threads, 32 rows/block, 68 KB LDS -> 2 blocks/CU.
//      __launch_bounds__(512,2): 2 BLOCKS/CU (CUDA semantics, verified R7:
//      (512,4) gave VGPR=64 = 4-blocks cap) -> 128-VGPR cap, no spill. ----
__global__ __launch_bounds__(512, 2)
void k_gemm(const float* __restrict__ Km, float* __restrict__ ws) {
    const int t    = threadIdx.x, b = blockIdx.x;
    const int lane = t & 63, w = t >> 6;      // 8 waves
    const int rb   = b >> 2, kb = b & 3;      // 128 row-blocks x 4 k-blocks
    const int row0 = rb*32 + w*4;             // 4 rows per wave

    const float* r_ = ws + O_R;
    float* wp = ws + O_W0 + kb*NTOT;

    __shared__ float rl[TT*KSL];              // [c][k], 68 KB; reused for reduce
    __shared__ float redd[TT], redg[TT];

    // K prefetch for chunks 0,1 first (overlaps staging)
    const float* Kb = Km + (size_t)row0*NN + kb*KSL + 4*lane;
    float4 kv[4], kvn[4];
    #pragma unroll
    for (int rr = 0; rr < 4; ++rr) kv[rr]  = *(const float4*)(Kb + rr*NN);
    #pragma unroll
    for (int rr = 0; rr < 4; ++rr) kvn[rr] = *(const float4*)(Kb + rr*NN + 256);

    if (t < TT) { redd[t] = 0.f; redg[t] = 0.f; }
    // stage r slice to LDS (coalesced float4)
    for (int v = t; v < TT*(KSL/4); v += 512) {
        int c = v >> 8, kq = (v & 255) << 2;
        *(float4*)(rl + c*KSL + kq) = *(const float4*)(r_ + c*NN + kb*KSL + kq);
    }
    __syncthreads();

    float acc[4][TT];
    #pragma unroll
    for (int rr = 0; rr < 4; ++rr)
        #pragma unroll
        for (int c = 0; c < TT; ++c) acc[rr][c] = 0.f;

    for (int ch = 0; ch < 4; ++ch) {          // 4 chunks x 256 k
        float4 kvt[4];
        if (ch + 2 < 4) {
            #pragma unroll
            for (int rr = 0; rr < 4; ++rr)
                kvt[rr] = *(const float4*)(Kb + rr*NN + (ch+2)*256);
        }
        const float* rlc = rl + ch*256 + 4*lane;
        #pragma unroll
        for (int c = 0; c < TT; ++c) {
            float4 rv = *(const float4*)(rlc + c*KSL);
            #pragma unroll
            for (int rr = 0; rr < 4; ++rr)
                acc[rr][c] += kv[rr].x*rv.x + kv[rr].y*rv.y + kv[rr].z*rv.z + kv[rr].w*rv.w;
        }
        #pragma unroll
        for (int rr = 0; rr < 4; ++rr) { kv[rr] = kvn[rr]; kvn[rr] = kvt[rr]; }
    }

    // partial butterfly: 64 -> 16 lane-classes (2 stages instead of 6)
    #pragma unroll
    for (int rr = 0; rr < 4; ++rr)
        #pragma unroll
        for (int c = 0; c < TT; ++c) {
            float v = acc[rr][c];
            v += __shfl_xor(v, 32, 64);
            v += __shfl_xor(v, 16, 64);
            acc[rr][c] = v;
        }

    __syncthreads();                          // all waves done reading rl
    float4* part2 = (float4*)rl;              // reuse: [w][c][16] float4(rr)
    if (lane < 16) {
        #pragma unroll
        for (int c = 0; c < TT; ++c)
            part2[(w*TT + c)*16 + lane] =
                make_float4(acc[0][c], acc[1][c], acc[2][c], acc[3][c]);
    }
    __syncthreads();

    if (t < 8*TT) {                           // 136 finish threads
        int w2 = t / TT, c2 = t % TT;
        float4 s = make_float4(0.f, 0.f, 0.f, 0.f);
        #pragma unroll
        for (int i = 0; i < 16; ++i) {
            float4 u = part2[(w2*TT + c2)*16 + i];
            s.x += u.x; s.y += u.y; s.z += u.z; s.w += u.w;
        }
        int row = rb*32 + w2*4;
        *(float4*)(wp + c2*NN + row) = s;     // dwordx4 partial write
        float4 rv = *(const float4*)(r_ + c2*NN + row);
        float dp = rv.x*s.x + rv.y*s.y + rv.z*s.z + rv.w*s.w;
        float gp = rv.x*rv.x + rv.y*rv.y + rv.z*rv.z + rv.w*rv.w;
        atomicAdd(&redd[c2], dp);
        if (kb == 0) atomicAdd(&redg[c2], gp);
    }
    __syncthreads();
    if (t < TT) {
        ws[O_PART + b*64 + t]      = redd[t];
        ws[O_PART + b*64 + 32 + t] = (kb == 0) ? redg[t] : 0.f;
    }
}

// ---- per-iter: reduce 512 partial slots, compute alpha/beta (pipelined CG) ----
__global__ void k_red(const float* __restrict__ noise, float* __restrict__ ws, int it) {
    __shared__ float sm[8][64];
    int t = threadIdx.x, seg = t >> 6, j = t & 63;   // 512 threads, 8 segments
    float s = 0.f;
    if (j < TT || (j >= 32 && j < 32 + TT)) {
        for (int i = 0; i < 64; ++i)
            s += ws[O_PART + (seg*64 + i)*64 + j];
    }
    sm[seg][j] = s;
    __syncthreads();
    if (t < TT) {
        float del = 0.f, gam = 0.f;
        #pragma unroll
        for (int g = 0; g < 8; ++g) { del += sm[g][t]; gam += sm[g][32 + t]; }
        float s2 = noise[0]*noise[0];
        float delta = del + s2*gam;               // r^T (K + s2 I) r
        float beta = 0.f, D = delta;
        if (it > 0) {
            float gp = ws[O_APGP + 32 + t];
            beta = (fabsf(gp) < 1e-30f) ? 0.f : gam/gp;
            float ap = ws[O_APGP + t];
            D = delta - ((fabsf(ap) < 1e-30f) ? 0.f : beta*gam/ap);
        }
        float alpha = (fabsf(D) < 1e-30f) ? 0.f : gam/D;
        ws[O_ALBE + t] = alpha; ws[O_ALBE + 32 + t] = beta;
        ws[O_APGP + t] = alpha; ws[O_APGP + 32 + t] = gam;
    }
}

// ---- per-iter: element-wise p,s,x,r updates (fully coalesced, [c][n] linear) ----
__global__ void k_upd(const float* __restrict__ noise, float* __restrict__ ws,
                      float* __restrict__ out, int last) {
    int e = blockIdx.x*256 + threadIdx.x;     // 272*256 == NTOT
    int c = e >> 12, n = e & (NN-1);
    float s2 = noise[0]*noise[0];
    float al = ws[O_ALBE + c], be = ws[O_ALBE + 32 + c];
    float rv = ws[O_R + e];
    float wv = ws[O_W0 + e] + ws[O_W0 + NTOT + e]
             + ws[O_W0 + 2*NTOT + e] + ws[O_W0 + 3*NTOT + e] + s2*rv;
    float pn = rv + be*ws[O_P + e];
    float sn = wv + be*ws[O_S + e];
    float xn = ws[O_X + e] + al*pn;
    float rn = rv - al*sn;
    ws[O_P + e] = pn; ws[O_S + e] = sn; ws[O_X + e] = xn; ws[O_R + e] = rn;
    if (last) out[n*TT + c] = xn * ws[O_SC + 32 + c];
}

extern "C" void kernel_launch(void* const* d_in, const int* in_sizes, int n_in,
                              void* d_out, int out_size, void* d_ws, size_t ws_size,
                              hipStream_t stream) {
    const float* Km    = (const float*)d_in[0];
    const float* yv    = (const float*)d_in[1];
    const float* Zm    = (const float*)d_in[2];
    const float* noise = (const float*)d_in[3];
    float* out = (float*)d_out;
    float* ws  = (float*)d_ws;

    k_ssq  <<<16, 256, 0, stream>>>(yv, Zm, ws);
    k_scale<<<1,   64, 0, stream>>>(ws);
    k_init <<<272, 256, 0, stream>>>(yv, Zm, ws);
    for (int it = 0; it < NIT; ++it) {
        k_gemm<<<512, 512, 0, stream>>>(Km, ws);
        k_red <<<1,   512, 0, stream>>>(noise, ws, it);
        k_upd <<<272, 256, 0, stream>>>(noise, ws, out, it == NIT-1);
    }
}